// Round 9
// baseline (320.434 us; speedup 1.0000x reference)
//
#include <hip/hip_runtime.h>
#include <hip/hip_bf16.h>

#define T_STEPS 128
#define D_IN    300
#define H_DIM   100
#define KDIM    400
#define WK      416            // W row stride (ushorts): 13 K-steps of 32
#define XK      288            // x-main K region (9 K-steps)
#define MROWS   16             // batch rows per block
#define XROW    296            // xmain row stride (ushorts; 592B -> conflict-free b128)
#define XSLOT   (MROWS * XROW)
#define HROW    136            // hbuf row: 12 x-tail + 100 h + 24 zeros (272B rows)
#define HSLOT   (MROWS * HROW)
#define BLOCK   256            // 4 waves, 1/SIMD -> full 512-reg unified budget
#define NRES    6              // resident W tiles per wave (4*6=24; tile 24 via LDS)
#define LN2E    1.44269504f
#define LN2E2   2.88539008f

typedef __attribute__((ext_vector_type(8))) short bf16x8;
typedef __attribute__((ext_vector_type(4))) float f32x4;

__device__ __forceinline__ ushort f2bf(float f) {
    uint u = __float_as_uint(f);
    u += 0x7FFFu + ((u >> 16) & 1u);     // RNE (prepass only)
    return (ushort)(u >> 16);
}
__device__ __forceinline__ uint cvt_pk_bf16(float lo, float hi) {
    uint r;
    asm("v_cvt_pk_bf16_f32 %0, %1, %2" : "=v"(r) : "v"(lo), "v"(hi));
    return r;
}

// Gate math, division-free. z pre-scaled by log2(e) (2*log2(e) for j),
// biases (incl. forget bias) folded into acc init. Updates c, returns h.
__device__ __forceinline__ float lstm_gate(const f32x4 z, float& c) {
    float ei = __builtin_amdgcn_exp2f(-z[0]);
    float ej = __builtin_amdgcn_exp2f(fminf(-z[1], 126.0f));
    float ef = __builtin_amdgcn_exp2f(-z[2]);
    float eo = __builtin_amdgcn_exp2f(-z[3]);
    float rf  = __builtin_amdgcn_rcpf(1.0f + ef);
    float rij = __builtin_amdgcn_rcpf((1.0f + ei) * (1.0f + ej));
    float c2 = c * rf + (1.0f - ej) * rij;
    c = c2;
    float ec = __builtin_amdgcn_exp2f(fminf(-LN2E2 * c2, 126.0f));
    return (1.0f - ec) * __builtin_amdgcn_rcpf((1.0f + ec) * (1.0f + eo));
}

// ---- Prepass: Wt[combo][p][k] bf16, p = 4*unit + gate, [n][k] layout, row WK=416,
// scaled by log2(e) (gate j: 2*log2(e)); k in [400,416) zeroed ----
__global__ __launch_bounds__(256) void prep_w(
    const float* __restrict__ W0, const float* __restrict__ W1,
    const float* __restrict__ W2, const float* __restrict__ W3,
    ushort* __restrict__ Wt)
{
    int idx = blockIdx.x * 256 + threadIdx.x;
    const int total = 4 * 400 * WK;
    if (idx >= total) return;
    int c   = idx / (400 * WK);
    int rem = idx - c * (400 * WK);
    int p   = rem / WK;
    int k   = rem - p * WK;
    const float* W = (c == 0) ? W0 : (c == 1) ? W1 : (c == 2) ? W2 : W3;
    const int g = p & 3;
    const float scale = (g == 1) ? LN2E2 : LN2E;
    float v = 0.0f;
    if (k < KDIM) v = W[k * 400 + g * 100 + (p >> 2)] * scale;
    Wt[idx] = f2bf(v);
}

__global__ __launch_bounds__(BLOCK, 1) void lstm_mfma(
    const float* __restrict__ premises,
    const float* __restrict__ hypotheses,
    const float* __restrict__ b0, const float* __restrict__ b1,
    const float* __restrict__ b2, const float* __restrict__ b3,
    const ushort* __restrict__ Wt,
    float* __restrict__ out)
{
    __shared__ ushort xmain[3 * XSLOT];   // x k<288, triple-buffered
    __shared__ ushort hbuf[2 * HSLOT];    // [x-tail(12) | h(100) | zeros(24)] ping-pong
    __shared__ ushort b24[13 * 512];      // tile-24 W frags: [ks][lane] 16B

    const int tid = threadIdx.x;
    const int l   = tid & 63;
    const int w   = tid >> 6;
    const int combo = blockIdx.y;
    const int row0  = blockIdx.x * MROWS;
    const bool backward = (combo & 1) != 0;
    const float* x    = (combo < 2) ? premises : hypotheses;
    const float* bias = (combo == 0) ? b0 : (combo == 1) ? b1 : (combo == 2) ? b2 : b3;
    const ushort* Wc  = Wt + (size_t)combo * 400 * WK;

    const int bn = l & 15;
    const int ul = l >> 4;

    // ---- resident W fragments (plain loads; allocator parks them in AGPRs,
    // MFMA reads AGPR A-operands natively) ----
    bf16x8 bfr[NRES][13];
    #pragma unroll
    for (int i = 0; i < NRES; ++i) {
        const ushort* bp = Wc + (size_t)((NRES * w + i) * 16 + bn) * WK + ul * 8;
        #pragma unroll
        for (int ks = 0; ks < 13; ++ks)
            bfr[i][ks] = *reinterpret_cast<const bf16x8*>(bp + ks * 32);
    }
    const bool hasS = (w == 3);          // wave 3 also runs tile 24 from LDS
    if (w == 0) {
        const ushort* bp = Wc + (size_t)(24 * 16 + bn) * WK + ul * 8;
        #pragma unroll
        for (int ks = 0; ks < 13; ++ks)
            *reinterpret_cast<bf16x8*>(&b24[ks * 512 + l * 8]) =
                *reinterpret_cast<const bf16x8*>(bp + ks * 32);
    }

    // ---- per-lane bias (acc-init) ----
    float bv[NRES][4], bvS[4] = {0.f, 0.f, 0.f, 0.f};
    #pragma unroll
    for (int i = 0; i < NRES; ++i) {
        int u = (NRES * w + i) * 4 + ul;
        bv[i][0] = LN2E * bias[u];
        bv[i][1] = LN2E2 * bias[100 + u];
        bv[i][2] = LN2E * (bias[200 + u] + 1.0f);
        bv[i][3] = LN2E * bias[300 + u];
    }
    if (hasS) {
        int u = 96 + ul;
        bvS[0] = LN2E * bias[u];
        bvS[1] = LN2E2 * bias[100 + u];
        bvS[2] = LN2E * (bias[200 + u] + 1.0f);
        bvS[3] = LN2E * bias[300 + u];
    }

    // ---- staging roles: main (all 256 threads, 5 chunks of 72/row), tail (48 thr) ----
    int MR[5], MD[5];
    bool MV[5];
    #pragma unroll
    for (int j = 0; j < 5; ++j) {
        int c = tid + j * 256;
        MV[j] = (c < 1152);
        MR[j] = c / 72;
        MD[j] = c - MR[j] * 72;
    }
    const bool tv = (tid < 48);
    const int TR = tid / 3, TD = tid - TR * 3;

    float4 T1, T2;

    // ---- prologue: x_0 -> xmain[0] (+tail->hbuf[0]); x_1 -> xmain[1] (tail kept in T1) ----
    for (int s = 0; s < 2; ++s) {
        int tt = backward ? (T_STEPS - 1 - s) : s;
        #pragma unroll
        for (int j = 0; j < 5; ++j)
            if (MV[j]) {
                float4 v = *reinterpret_cast<const float4*>(
                    x + ((size_t)(row0 + MR[j]) * T_STEPS + tt) * D_IN + MD[j] * 4);
                uint2 q;
                q.x = cvt_pk_bf16(v.x, v.y);
                q.y = cvt_pk_bf16(v.z, v.w);
                *reinterpret_cast<uint2*>(&xmain[s * XSLOT + MR[j] * XROW + MD[j] * 4]) = q;
            }
        if (tv) {
            float4 v = *reinterpret_cast<const float4*>(
                x + ((size_t)(row0 + TR) * T_STEPS + tt) * D_IN + XK + TD * 4);
            if (s == 0) {
                uint2 q;
                q.x = cvt_pk_bf16(v.x, v.y);
                q.y = cvt_pk_bf16(v.z, v.w);
                *reinterpret_cast<uint2*>(&hbuf[TR * HROW + TD * 4]) = q;
            } else {
                T1 = v;   // x_1 tail, written during epoch 0
            }
        }
    }
    // zeros: hbuf[0] h+pad region, hbuf[1] pad region
    for (int i = tid; i < MROWS * 124; i += BLOCK) {
        int r = i / 124;
        hbuf[r * HROW + 12 + (i - r * 124)] = 0;
    }
    for (int i = tid; i < MROWS * 24; i += BLOCK) {
        int r = i / 24;
        hbuf[HSLOT + r * HROW + 112 + (i - r * 24)] = 0;
    }
    __syncthreads();

    const uint xoff = (uint)(l & 15) * XROW + (uint)ul * 8;
    const uint hoff = (uint)(l & 15) * HROW + (uint)ul * 8;
    const int  row  = l & 15;

    // ---- acc prologue: accA = bias + x-part(x_0) ----
    f32x4 accA[NRES], accB[NRES], accAS, accBS;
    #pragma unroll
    for (int i = 0; i < NRES; ++i)
        accA[i] = (f32x4){bv[i][0], bv[i][1], bv[i][2], bv[i][3]};
    accAS = (f32x4){bvS[0], bvS[1], bvS[2], bvS[3]};
    #pragma unroll
    for (int ks = 0; ks < 9; ++ks) {
        const bf16x8 a = *reinterpret_cast<const bf16x8*>(xmain + xoff + ks * 32);
        #pragma unroll
        for (int i = 0; i < NRES; ++i)
            accA[i] = __builtin_amdgcn_mfma_f32_16x16x32_bf16(bfr[i][ks], a, accA[i], 0, 0, 0);
        if (hasS) {
            const bf16x8 bs = *reinterpret_cast<const bf16x8*>(&b24[ks * 512 + l * 8]);
            accAS = __builtin_amdgcn_mfma_f32_16x16x32_bf16(bs, a, accAS, 0, 0, 0);
        }
    }

    float creg[NRES];
    #pragma unroll
    for (int i = 0; i < NRES; ++i) creg[i] = 0.f;
    float cregS = 0.f;

    auto body = [&](int t, f32x4 (&accC)[NRES], f32x4& accCS,
                           f32x4 (&accN)[NRES], f32x4& accNS,
                           float4& Tw, float4& Ti) {
        // issue x_{t+2} (main + tail) — written at epoch end / next epoch
        float4 M[5];
        if (t <= T_STEPS - 3) {
            int tn = backward ? (T_STEPS - 3 - t) : (t + 2);
            #pragma unroll
            for (int j = 0; j < 5; ++j)
                if (MV[j])
                    M[j] = *reinterpret_cast<const float4*>(
                        x + ((size_t)(row0 + MR[j]) * T_STEPS + tn) * D_IN + MD[j] * 4);
            if (tv)
                Ti = *reinterpret_cast<const float4*>(
                    x + ((size_t)(row0 + TR) * T_STEPS + tn) * D_IN + XK + TD * 4);
        }

        // ph1: h-part (+x-tail) MFMAs -> complete accC   (critical path)
        const ushort* hb = hbuf + (t & 1) * HSLOT;
        #pragma unroll
        for (int ks = 0; ks < 4; ++ks) {
            const bf16x8 a = *reinterpret_cast<const bf16x8*>(hb + hoff + ks * 32);
            #pragma unroll
            for (int i = 0; i < NRES; ++i)
                accC[i] = __builtin_amdgcn_mfma_f32_16x16x32_bf16(bfr[i][9 + ks], a, accC[i], 0, 0, 0);
            if (hasS) {
                const bf16x8 bs = *reinterpret_cast<const bf16x8*>(&b24[(9 + ks) * 512 + l * 8]);
                accCS = __builtin_amdgcn_mfma_f32_16x16x32_bf16(bs, a, accCS, 0, 0, 0);
            }
        }

        // ph2: gates -> h_t -> hbuf[(t+1)&1]; tail-stagers write x_{t+1} tail
        ushort* hw = hbuf + ((t + 1) & 1) * HSLOT;
        #pragma unroll
        for (int i = 0; i < NRES; ++i) {
            float h = lstm_gate(accC[i], creg[i]);
            hw[row * HROW + 12 + (NRES * w + i) * 4 + ul] =
                (ushort)(cvt_pk_bf16(h, h) & 0xFFFFu);
        }
        if (hasS) {
            float hS = lstm_gate(accCS, cregS);
            hw[row * HROW + 12 + 96 + ul] = (ushort)(cvt_pk_bf16(hS, hS) & 0xFFFFu);
        }
        if (tv && t <= T_STEPS - 2) {
            uint2 q;
            q.x = cvt_pk_bf16(Tw.x, Tw.y);
            q.y = cvt_pk_bf16(Tw.z, Tw.w);
            *reinterpret_cast<uint2*>(&hw[TR * HROW + TD * 4]) = q;
        }

        // ph3: x-part of step t+1 -> accN (off the critical path)
        if (t <= T_STEPS - 2) {
            const ushort* xr = xmain + ((t + 1) % 3) * XSLOT;
            #pragma unroll
            for (int i = 0; i < NRES; ++i)
                accN[i] = (f32x4){bv[i][0], bv[i][1], bv[i][2], bv[i][3]};
            accNS = (f32x4){bvS[0], bvS[1], bvS[2], bvS[3]};
            #pragma unroll
            for (int ks = 0; ks < 9; ++ks) {
                const bf16x8 a = *reinterpret_cast<const bf16x8*>(xr + xoff + ks * 32);
                #pragma unroll
                for (int i = 0; i < NRES; ++i)
                    accN[i] = __builtin_amdgcn_mfma_f32_16x16x32_bf16(bfr[i][ks], a, accN[i], 0, 0, 0);
                if (hasS) {
                    const bf16x8 bs = *reinterpret_cast<const bf16x8*>(&b24[ks * 512 + l * 8]);
                    accNS = __builtin_amdgcn_mfma_f32_16x16x32_bf16(bs, a, accNS, 0, 0, 0);
                }
            }
        }

        // stage-write x_{t+2} main -> xmain[(t+2)%3]
        if (t <= T_STEPS - 3) {
            ushort* xw = xmain + ((t + 2) % 3) * XSLOT;
            #pragma unroll
            for (int j = 0; j < 5; ++j)
                if (MV[j]) {
                    uint2 q;
                    q.x = cvt_pk_bf16(M[j].x, M[j].y);
                    q.y = cvt_pk_bf16(M[j].z, M[j].w);
                    *reinterpret_cast<uint2*>(&xw[MR[j] * XROW + MD[j] * 4]) = q;
                }
        }
        __syncthreads();
    };

    for (int t = 0; t < T_STEPS; t += 2) {
        body(t,     accA, accAS, accB, accBS, T1, T2);
        body(t + 1, accB, accBS, accA, accAS, T2, T1);
    }

    // ---- final c write ----
    #pragma unroll
    for (int i = 0; i < NRES; ++i)
        out[(size_t)(row0 + row) * 400 + combo * 100 + (NRES * w + i) * 4 + ul] = creg[i];
    if (hasS)
        out[(size_t)(row0 + row) * 400 + combo * 100 + 96 + ul] = cregS;
}

extern "C" void kernel_launch(void* const* d_in, const int* in_sizes, int n_in,
                              void* d_out, int out_size, void* d_ws, size_t ws_size,
                              hipStream_t stream) {
    const float* premises   = (const float*)d_in[0];
    const float* hypotheses = (const float*)d_in[1];
    const float* Wp_fw = (const float*)d_in[2];
    const float* bp_fw = (const float*)d_in[3];
    const float* Wp_bw = (const float*)d_in[4];
    const float* bp_bw = (const float*)d_in[5];
    const float* Wh_fw = (const float*)d_in[6];
    const float* bh_fw = (const float*)d_in[7];
    const float* Wh_bw = (const float*)d_in[8];
    const float* bh_bw = (const float*)d_in[9];
    float* out = (float*)d_out;
    ushort* Wt = (ushort*)d_ws;   // 4*400*416*2 = 1.33 MB

    {
        const int total = 4 * 400 * WK;
        prep_w<<<(total + 255) / 256, 256, 0, stream>>>(Wp_fw, Wp_bw, Wh_fw, Wh_bw, Wt);
    }
    dim3 grid(1024 / MROWS, 4);
    lstm_mfma<<<grid, dim3(BLOCK), 0, stream>>>(
        premises, hypotheses,
        bp_fw, bp_bw, bh_fw, bh_bw,
        Wt, out);
}